// Round 2
// baseline (205.487 us; speedup 1.0000x reference)
//
#include <hip/hip_runtime.h>

// Problem constants (N=4096 rows, D=2048 cols, T=0.5 -> 1/T = 2)
#define NR 4096
#define DD 2048
#define INV_T 2.0f
// fp4 path (gemm): a_n*64 ~ N(0,1.41) into e2m1 range ±6 (±4.2 sigma);
// MFMA acc = 4096*sim
#define QS4 64.0f
#define ACC4_TO_LOGIT (INV_T / (QS4 * QS4))  // 2/4096, gemm logits

typedef __attribute__((ext_vector_type(2))) float floatx2;
typedef __attribute__((ext_vector_type(4))) float floatx4;
typedef __attribute__((ext_vector_type(16))) float floatx16;
typedef __attribute__((ext_vector_type(4))) int int4v;
typedef __attribute__((ext_vector_type(8))) int int8v;

static __device__ __forceinline__ void async_copy16(const void* g, void* lds) {
  __builtin_amdgcn_global_load_lds((const __attribute__((address_space(1))) void*)g,
                                   (__attribute__((address_space(3))) void*)lds,
                                   16, 0, 0);
}

// e2m1 encode of pre-scaled x: values {0,.5,1,1.5,2,3,4,6}, clamp at 6,
// round-to-nearest via midpoint thresholds. Returns 4-bit code.
static __device__ __forceinline__ unsigned int enc4(float x) {
  float u = fminf(fabsf(x), 6.0f);
  int c = (u >= 0.25f) + (u >= 0.75f) + (u >= 1.25f) + (u >= 1.75f) +
          (u >= 2.5f) + (u >= 3.5f) + (u >= 5.0f);
  return (unsigned)(c | (x < 0.f ? 8 : 0));
}

static __device__ __forceinline__ unsigned int pack8_fp4(
    const float4& v0, const float4& v1, float s) {
  return enc4(v0.x * s)        | (enc4(v0.y * s) << 4)  |
         (enc4(v0.z * s) << 8) | (enc4(v0.w * s) << 12) |
         (enc4(v1.x * s) << 16)| (enc4(v1.y * s) << 20) |
         (enc4(v1.z * s) << 24)| (enc4(v1.w * s) << 28);
}

// ---------------------------------------------------------------------------
// Kernel 0: zero s_a|s_b (4096 floats) + gemm completion counter. Separate
// dispatch: K1's colsum atomics would race with same-kernel zeroing.
// ---------------------------------------------------------------------------
__global__ __launch_bounds__(256) void zero_kernel(float* z) {
  #pragma unroll
  for (int i = 0; i < 4; i++)
    *(floatx4*)&z[4 * (threadIdx.x + 256 * i)] = floatx4{0.f, 0.f, 0.f, 0.f};
  if (threadIdx.x == 0) z[4096] = 0.f;  // counter
}

// ---------------------------------------------------------------------------
// Kernel 1: per-row L2 normalize + fused f32 column sums (r10, kept at r11).
// mean(sim_pos) = (sum_i a_n[i]) . (sum_j b_n[j]) / N^2.
// mat 0 (source):     fp4 row-major a4 (gemm) + colsum -> s_a
// mat 1 (bc_target):  colsum -> s_b only
// mat 2 (raw_target): fp4 row-major c4 (gemm)
// 16 rows/block, one row per wave-iteration. Reads 32B/lane contiguous.
// grid (256, 3), block 256 (768 blocks = exactly 3/CU, balanced).
// Near HBM roofline: 100.7MB reads @ ~6.3TB/s ~= 16us floor.
// ---------------------------------------------------------------------------
__global__ __launch_bounds__(256) void normalize_colsum_kernel(
    const float* __restrict__ src, const float* __restrict__ bc,
    const float* __restrict__ raw,
    unsigned int* __restrict__ a4, unsigned int* __restrict__ c4,
    float* __restrict__ s_a, float* __restrict__ s_b) {
  const int mat = blockIdx.y;
  const int tid = threadIdx.x;
  const int lane = tid & 63;
  const int wave = tid >> 6;
  const float* base = (mat == 0) ? src : ((mat == 1) ? bc : raw);
  unsigned int* q4 = (mat == 0) ? a4 : c4;  // unused for mat 1

  float acc[32];
  #pragma unroll
  for (int i = 0; i < 32; i++) acc[i] = 0.f;

  #pragma unroll
  for (int r = 0; r < 4; r++) {
    const int row = blockIdx.x * 16 + wave * 4 + r;
    const float4* rp = (const float4*)(base + (size_t)row * DD);
    float4 v[8];
    #pragma unroll
    for (int c = 0; c < 4; c++) {          // lane reads 32B contiguous /chunk
      v[2 * c]     = rp[lane * 2 + 128 * c];
      v[2 * c + 1] = rp[lane * 2 + 1 + 128 * c];
    }
    float ss = 0.f;
    #pragma unroll
    for (int c = 0; c < 8; c++)
      ss += v[c].x * v[c].x + v[c].y * v[c].y + v[c].z * v[c].z + v[c].w * v[c].w;
    #pragma unroll
    for (int off = 1; off < 64; off <<= 1) ss += __shfl_xor(ss, off, 64);
    const float sinv = rsqrtf(ss);

    if (mat != 2) {  // f32 colsum accumulate (exact)
      #pragma unroll
      for (int c = 0; c < 8; c++) {
        acc[c * 4 + 0] += v[c].x * sinv; acc[c * 4 + 1] += v[c].y * sinv;
        acc[c * 4 + 2] += v[c].z * sinv; acc[c * 4 + 3] += v[c].w * sinv;
      }
    }
    if (mat != 1) {  // fp4 pack for the gemm; dword d covers elts [8d,8d+8)
      const float s4 = sinv * QS4;
      #pragma unroll
      for (int c = 0; c < 4; c++)
        q4[row * 256 + lane + 64 * c] = pack8_fp4(v[2 * c], v[2 * c + 1], s4);
    }
  }
  if (mat == 2) return;  // uniform per block — no divergent barrier

  // cross-wave combine, then one device atomic per column per block.
  __shared__ float lsum[4][2048];
  #pragma unroll
  for (int c = 0; c < 4; c++) {
    *(floatx4*)&lsum[wave][8 * lane + 512 * c] =
        floatx4{acc[8 * c], acc[8 * c + 1], acc[8 * c + 2], acc[8 * c + 3]};
    *(floatx4*)&lsum[wave][8 * lane + 512 * c + 4] =
        floatx4{acc[8 * c + 4], acc[8 * c + 5], acc[8 * c + 6], acc[8 * c + 7]};
  }
  __syncthreads();
  float* dst = (mat == 0) ? s_a : s_b;
  #pragma unroll
  for (int k = 0; k < 8; k++) {
    const int col = tid + 256 * k;
    atomicAdd(&dst[col],
              lsum[0][col] + lsum[1][col] + lsum[2][col] + lsum[3][col]);
  }
}

// ---------------------------------------------------------------------------
// Kernel 2: MX-fp4 MFMA GEMM a_n @ c_n^T with fused sum(exp(sim/T)) epilogue
// + last-block-done finalize (r11).
// r11 changes vs r10:
//  * 32x32x64 fp4 MFMA (9.1 PF ubench) instead of 16x16x128 (7.2 PF):
//    floor 9.5us -> 7.5us, static MFMA count halves. Fragment map: lane
//    holds row lane&31, k-half lane>>5 -> logical chunk ch = s*2+(lane>>5),
//    same XOR swizzle; 8 lanes per 16B column = uniformly bank-balanced.
//    Epilogue sums ALL acc elements, so C/D layout is irrelevant.
//  * finalize folded in via last-block-done. S_part written with atomicExch
//    and read with atomicAdd(p,0) (coherence point — per-XCD L2s are not
//    cross-coherent for plain stores within a kernel). s_a/s_b are from the
//    previous dispatch -> plain reads safe.
// Keeps: dbuf, XOR source-swizzle, bijective XCD-chunk swizzle (per-XCD
// working set 3MB < 4MB L2), occupancy 2.
// grid (32, 32), block 256 (4 waves; each wave owns a 64x64 quadrant).
// ---------------------------------------------------------------------------
__global__ __launch_bounds__(256, 2) void gemm_expsum_kernel(
    const unsigned char* __restrict__ a4, const unsigned char* __restrict__ c4,
    float* __restrict__ S_part, float* __restrict__ counter,
    const float* __restrict__ s_a, const float* __restrict__ s_b,
    float* __restrict__ out) {
  __shared__ unsigned char As[2][128 * 128];  // [buf][row][chunk^(row&7)]
  __shared__ unsigned char Cs[2][128 * 128];
  const int tid = threadIdx.x;
  const int lane = tid & 63;
  const int wave = tid >> 6;
  const int wr = wave >> 1;       // wave row quadrant (0/1)
  const int wc = wave & 1;        // wave col quadrant (0/1)
  const int half = lane >> 5;     // k-half selector within a k-step (K=64)
  const int l32 = lane & 31;

  // XCD-chunked swizzle (bijective: 1024 = 8 chunks x 128 blocks)
  const int lin = blockIdx.y * 32 + blockIdx.x;
  const int xcd = lin & 7;        // HW assigns lin -> XCD round-robin
  const int idx = lin >> 3;       // 0..127 within this XCD's chunk
  const int br = (xcd >> 1) * 8 + (idx >> 4);   // 4 chunk-rows of 8
  const int bc = (xcd & 1) * 16 + (idx & 15);   // 2 chunk-cols of 16

  floatx16 acc[2][2] = {};

  // staging: per matrix+buffer, 16 windows of 1KB (8 rows x 128B); 4/wave.
  // fp4 row = 1024B; ktile kt covers row bytes [kt*128, kt*128+128).
  const int wrow = lane >> 3;
  const int csrc = (lane & 7) ^ (wrow & 7);
  const unsigned char* gA[4];
  const unsigned char* gC[4];
  int ldsOff[4];
  #pragma unroll
  for (int q = 0; q < 4; q++) {
    const int m = wave * 4 + q;
    const int row = m * 8 + wrow;
    gA[q] = a4 + (size_t)(br * 128 + row) * 1024 + csrc * 16;
    gC[q] = c4 + (size_t)(bc * 128 + row) * 1024 + csrc * 16;
    ldsOff[q] = m * 1024;
  }

  // prologue: stage ktile 0 into buffer 0
  #pragma unroll
  for (int q = 0; q < 4; q++) {
    async_copy16(gA[q], &As[0][ldsOff[q]]);
    async_copy16(gC[q], &Cs[0][ldsOff[q]]);
    gA[q] += 128; gC[q] += 128;
  }

  const int NKT = DD / 256;  // 8 ktiles
  #pragma unroll 2
  for (int kt = 0; kt < NKT; kt++) {
    const int cur = kt & 1;
    __syncthreads();  // drains vmcnt: ktile-kt stage (issued one body ago)

    if (kt < NKT - 1) {  // prefetch kt+1 into the other buffer
      #pragma unroll
      for (int q = 0; q < 4; q++) {
        async_copy16(gA[q], &As[cur ^ 1][ldsOff[q]]);
        async_copy16(gC[q], &Cs[cur ^ 1][ldsOff[q]]);
        gA[q] += 128; gC[q] += 128;
      }
    }

    // fragments: k-step s (64 k-elems = 32B/row), lane(half,l32): 32 nibbles
    // = 16B at logical chunk s*2+half (physical ^(r&7)). fp4 uses v[0:3].
    int4v af[4][2], bf[4][2];
    #pragma unroll
    for (int s = 0; s < 4; s++) {
      #pragma unroll
      for (int i = 0; i < 2; i++) {
        const int r = wr * 64 + i * 32 + l32;
        const int pc = (s * 2 + half) ^ (r & 7);
        af[s][i] = *(const int4v*)&As[cur][r * 128 + pc * 16];
      }
      #pragma unroll
      for (int j = 0; j < 2; j++) {
        const int r = wc * 64 + j * 32 + l32;
        const int pc = (s * 2 + half) ^ (r & 7);
        bf[s][j] = *(const int4v*)&Cs[cur][r * 128 + pc * 16];
      }
    }
    #pragma unroll
    for (int s = 0; s < 4; s++)
      #pragma unroll
      for (int i = 0; i < 2; i++) {
        const int8v a8v = int8v{af[s][i][0], af[s][i][1], af[s][i][2],
                                af[s][i][3], 0, 0, 0, 0};
        #pragma unroll
        for (int j = 0; j < 2; j++) {
          const int8v b8v = int8v{bf[s][j][0], bf[s][j][1], bf[s][j][2],
                                  bf[s][j][3], 0, 0, 0, 0};
          acc[i][j] = __builtin_amdgcn_mfma_scale_f32_32x32x64_f8f6f4(
              a8v, b8v, acc[i][j], 4 /*cbsz: fp4*/, 4 /*blgp: fp4*/,
              0, 0x7F7F7F7F, 0, 0x7F7F7F7F /*E8M0 identity scales*/);
        }
      }
  }

  // epilogue: sum exp(sim/T) over this block's 128x128 tile; acc = 4096*sim.
  float local = 0.f;
  #pragma unroll
  for (int i = 0; i < 2; i++)
    #pragma unroll
    for (int j = 0; j < 2; j++)
      #pragma unroll
      for (int r = 0; r < 16; r++)
        local += __expf(acc[i][j][r] * ACC4_TO_LOGIT);
  #pragma unroll
  for (int off = 32; off > 0; off >>= 1) local += __shfl_down(local, off, 64);
  __shared__ float red[4];
  if (lane == 0) red[wave] = local;
  __syncthreads();
  // device-coherent publish (atomicExch goes to the coherence point; plain
  // stores could linger in this XCD's L2, invisible to the last block)
  if (tid == 0)
    atomicExch(&S_part[br * 32 + bc], red[0] + red[1] + red[2] + red[3]);

  // ---- last-block-done finalize ----
  __threadfence();
  __syncthreads();
  __shared__ bool amLast;
  if (tid == 0) amLast = (atomicAdd(counter, 1.0f) == 1023.0f);
  __syncthreads();
  if (!amLast) return;
  __threadfence();  // acquire side

  float dot = 0.f, se = 0.f;
  #pragma unroll
  for (int k = 0; k < 8; k++)
    dot += s_a[tid + 256 * k] * s_b[tid + 256 * k];  // prev dispatch: plain ok
  #pragma unroll
  for (int k = 0; k < 4; k++)
    se += atomicAdd(&S_part[tid + 256 * k], 0.f);    // coherent reads
  #pragma unroll
  for (int off = 32; off > 0; off >>= 1) {
    dot += __shfl_down(dot, off, 64);
    se  += __shfl_down(se, off, 64);
  }
  __shared__ float redd[4], reds[4];
  if ((tid & 63) == 0) { redd[tid >> 6] = dot; reds[tid >> 6] = se; }
  __syncthreads();
  if (tid == 0) {
    const float dt = redd[0] + redd[1] + redd[2] + redd[3];
    const float st = reds[0] + reds[1] + reds[2] + reds[3];
    // loss = log(sum exp(sim_neg/T)) - mean(sim_pos)/T
    out[0] = logf(st) - dt * (INV_T / ((float)NR * (float)NR));
  }
}

extern "C" void kernel_launch(void* const* d_in, const int* in_sizes, int n_in,
                              void* d_out, int out_size, void* d_ws, size_t ws_size,
                              hipStream_t stream) {
  const float* src = (const float*)d_in[0];
  const float* bc  = (const float*)d_in[1];
  const float* raw = (const float*)d_in[2];

  char* ws = (char*)d_ws;
  unsigned int* a4 = (unsigned int*)ws;                             // 4 MiB
  unsigned int* c4 = (unsigned int*)(ws + (size_t)4 * 1024 * 1024); // 4 MiB
  float* zb  = (float*)(ws + (size_t)8 * 1024 * 1024);  // s_a|s_b|counter
  float* s_a = zb;
  float* s_b = zb + DD;
  float* counter = zb + 2 * DD;
  float* S_part = (float*)(ws + (size_t)8 * 1024 * 1024 + 32 * 1024);  // 4 KiB

  zero_kernel<<<1, 256, 0, stream>>>(zb);
  normalize_colsum_kernel<<<dim3(NR / 16, 3), 256, 0, stream>>>(
      src, bc, raw, a4, c4, s_a, s_b);
  gemm_expsum_kernel<<<dim3(32, 32), 256, 0, stream>>>(
      (const unsigned char*)a4, (const unsigned char*)c4, S_part, counter,
      s_a, s_b, (float*)d_out);
}

// Round 3
// 146.958 us; speedup vs baseline: 1.3983x; 1.3983x over previous
//
#include <hip/hip_runtime.h>

// Problem constants (N=4096 rows, D=2048 cols, T=0.5 -> 1/T = 2)
#define NR 4096
#define DD 2048
#define INV_T 2.0f
// fp4 path (gemm): a_n*64 ~ N(0,1.41) into e2m1 range ±6 (±4.2 sigma);
// MFMA acc = 4096*sim
#define QS4 64.0f
#define ACC4_TO_LOGIT (INV_T / (QS4 * QS4))  // 2/4096, gemm logits

typedef __attribute__((ext_vector_type(2))) float floatx2;
typedef __attribute__((ext_vector_type(4))) float floatx4;
typedef __attribute__((ext_vector_type(16))) float floatx16;
typedef __attribute__((ext_vector_type(4))) int int4v;
typedef __attribute__((ext_vector_type(8))) int int8v;

static __device__ __forceinline__ void async_copy16(const void* g, void* lds) {
  __builtin_amdgcn_global_load_lds((const __attribute__((address_space(1))) void*)g,
                                   (__attribute__((address_space(3))) void*)lds,
                                   16, 0, 0);
}

// e2m1 encode of pre-scaled x: values {0,.5,1,1.5,2,3,4,6}, clamp at 6,
// round-to-nearest via midpoint thresholds. Returns 4-bit code.
static __device__ __forceinline__ unsigned int enc4(float x) {
  float u = fminf(fabsf(x), 6.0f);
  int c = (u >= 0.25f) + (u >= 0.75f) + (u >= 1.25f) + (u >= 1.75f) +
          (u >= 2.5f) + (u >= 3.5f) + (u >= 5.0f);
  return (unsigned)(c | (x < 0.f ? 8 : 0));
}

static __device__ __forceinline__ unsigned int pack8_fp4(
    const float4& v0, const float4& v1, float s) {
  return enc4(v0.x * s)        | (enc4(v0.y * s) << 4)  |
         (enc4(v0.z * s) << 8) | (enc4(v0.w * s) << 12) |
         (enc4(v1.x * s) << 16)| (enc4(v1.y * s) << 20) |
         (enc4(v1.z * s) << 24)| (enc4(v1.w * s) << 28);
}

// ---------------------------------------------------------------------------
// Kernel 0: zero s_a|s_b (4096 floats). Separate dispatch: K1's colsum
// atomics would race with same-kernel zeroing.
// ---------------------------------------------------------------------------
__global__ __launch_bounds__(256) void zero_kernel(float* z) {
  #pragma unroll
  for (int i = 0; i < 4; i++)
    *(floatx4*)&z[4 * (threadIdx.x + 256 * i)] = floatx4{0.f, 0.f, 0.f, 0.f};
}

// ---------------------------------------------------------------------------
// Kernel 1: per-row L2 normalize + fused f32 column sums (r10 structure).
// mean(sim_pos) = (sum_i a_n[i]) . (sum_j b_n[j]) / N^2.
// mat 0 (source):     fp4 row-major a4 (gemm) + colsum -> s_a
// mat 1 (bc_target):  colsum -> s_b only
// mat 2 (raw_target): fp4 row-major c4 (gemm)
// 16 rows/block, one row per wave-iteration. Reads 32B/lane contiguous.
// grid (256, 3), block 256. Near HBM roofline (~16us floor for 100.7MB).
// ---------------------------------------------------------------------------
__global__ __launch_bounds__(256) void normalize_colsum_kernel(
    const float* __restrict__ src, const float* __restrict__ bc,
    const float* __restrict__ raw,
    unsigned int* __restrict__ a4, unsigned int* __restrict__ c4,
    float* __restrict__ s_a, float* __restrict__ s_b) {
  const int mat = blockIdx.y;
  const int tid = threadIdx.x;
  const int lane = tid & 63;
  const int wave = tid >> 6;
  const float* base = (mat == 0) ? src : ((mat == 1) ? bc : raw);
  unsigned int* q4 = (mat == 0) ? a4 : c4;  // unused for mat 1

  float acc[32];
  #pragma unroll
  for (int i = 0; i < 32; i++) acc[i] = 0.f;

  #pragma unroll
  for (int r = 0; r < 4; r++) {
    const int row = blockIdx.x * 16 + wave * 4 + r;
    const float4* rp = (const float4*)(base + (size_t)row * DD);
    float4 v[8];
    #pragma unroll
    for (int c = 0; c < 4; c++) {          // lane reads 32B contiguous /chunk
      v[2 * c]     = rp[lane * 2 + 128 * c];
      v[2 * c + 1] = rp[lane * 2 + 1 + 128 * c];
    }
    float ss = 0.f;
    #pragma unroll
    for (int c = 0; c < 8; c++)
      ss += v[c].x * v[c].x + v[c].y * v[c].y + v[c].z * v[c].z + v[c].w * v[c].w;
    #pragma unroll
    for (int off = 1; off < 64; off <<= 1) ss += __shfl_xor(ss, off, 64);
    const float sinv = rsqrtf(ss);

    if (mat != 2) {  // f32 colsum accumulate (exact)
      #pragma unroll
      for (int c = 0; c < 8; c++) {
        acc[c * 4 + 0] += v[c].x * sinv; acc[c * 4 + 1] += v[c].y * sinv;
        acc[c * 4 + 2] += v[c].z * sinv; acc[c * 4 + 3] += v[c].w * sinv;
      }
    }
    if (mat != 1) {  // fp4 pack for the gemm; dword d covers elts [8d,8d+8)
      const float s4 = sinv * QS4;
      #pragma unroll
      for (int c = 0; c < 4; c++)
        q4[row * 256 + lane + 64 * c] = pack8_fp4(v[2 * c], v[2 * c + 1], s4);
    }
  }
  if (mat == 2) return;  // uniform per block — no divergent barrier

  // cross-wave combine, then one device atomic per column per block.
  __shared__ float lsum[4][2048];
  #pragma unroll
  for (int c = 0; c < 4; c++) {
    *(floatx4*)&lsum[wave][8 * lane + 512 * c] =
        floatx4{acc[8 * c], acc[8 * c + 1], acc[8 * c + 2], acc[8 * c + 3]};
    *(floatx4*)&lsum[wave][8 * lane + 512 * c + 4] =
        floatx4{acc[8 * c + 4], acc[8 * c + 5], acc[8 * c + 6], acc[8 * c + 7]};
  }
  __syncthreads();
  float* dst = (mat == 0) ? s_a : s_b;
  #pragma unroll
  for (int k = 0; k < 8; k++) {
    const int col = tid + 256 * k;
    atomicAdd(&dst[col],
              lsum[0][col] + lsum[1][col] + lsum[2][col] + lsum[3][col]);
  }
}

// ---------------------------------------------------------------------------
// Kernel 2: MX-fp4 MFMA GEMM a_n @ c_n^T with fused sum(exp(sim/T)) epilogue.
// r12: SINGLE-VARIABLE unbundle of the r11 6x regression (93.5us gemm,
// MfmaUtil 7%, all pipes idle -> stall-bound, not compute/LDS):
//  * REVERTED: fused last-block finalize. Its __threadfence (buffer_wbl2/
//    buffer_inv per wave x 4096 waves) serialized at the TCCs and
//    invalidated the L2-resident operand set — prime suspect. Back to plain
//    S_part store + separate 1-block finalize (kernel-boundary coherence).
//  * KEPT: 32x32x64 fp4 MFMA (9.1 PF pipe vs 7.2 for 16x16x128). Counters
//    showed its pipe-time ≈ ideal (6.6us vs 7.5 ideal), so the shape is
//    innocent of the stall. If this round still regresses vs 149us, the
//    shape is guilty -> revert next.
// Keeps: dbuf, XOR source-swizzle, bijective XCD-chunk swizzle, occupancy 2.
// grid (32, 32), block 256 (4 waves; each wave owns a 64x64 quadrant).
// ---------------------------------------------------------------------------
__global__ __launch_bounds__(256, 2) void gemm_expsum_kernel(
    const unsigned char* __restrict__ a4, const unsigned char* __restrict__ c4,
    float* __restrict__ S_part) {
  __shared__ unsigned char As[2][128 * 128];  // [buf][row][chunk^(row&7)]
  __shared__ unsigned char Cs[2][128 * 128];
  const int tid = threadIdx.x;
  const int lane = tid & 63;
  const int wave = tid >> 6;
  const int wr = wave >> 1;       // wave row quadrant (0/1)
  const int wc = wave & 1;        // wave col quadrant (0/1)
  const int half = lane >> 5;     // k-half selector within a k-step (K=64)
  const int l32 = lane & 31;

  // XCD-chunked swizzle (bijective: 1024 = 8 chunks x 128 blocks)
  const int lin = blockIdx.y * 32 + blockIdx.x;
  const int xcd = lin & 7;        // HW assigns lin -> XCD round-robin
  const int idx = lin >> 3;       // 0..127 within this XCD's chunk
  const int br = (xcd >> 1) * 8 + (idx >> 4);   // 4 chunk-rows of 8
  const int bc = (xcd & 1) * 16 + (idx & 15);   // 2 chunk-cols of 16

  floatx16 acc[2][2] = {};

  // staging: per matrix+buffer, 16 windows of 1KB (8 rows x 128B); 4/wave.
  // fp4 row = 1024B; ktile kt covers row bytes [kt*128, kt*128+128).
  const int wrow = lane >> 3;
  const int csrc = (lane & 7) ^ (wrow & 7);
  const unsigned char* gA[4];
  const unsigned char* gC[4];
  int ldsOff[4];
  #pragma unroll
  for (int q = 0; q < 4; q++) {
    const int m = wave * 4 + q;
    const int row = m * 8 + wrow;
    gA[q] = a4 + (size_t)(br * 128 + row) * 1024 + csrc * 16;
    gC[q] = c4 + (size_t)(bc * 128 + row) * 1024 + csrc * 16;
    ldsOff[q] = m * 1024;
  }

  // prologue: stage ktile 0 into buffer 0
  #pragma unroll
  for (int q = 0; q < 4; q++) {
    async_copy16(gA[q], &As[0][ldsOff[q]]);
    async_copy16(gC[q], &Cs[0][ldsOff[q]]);
    gA[q] += 128; gC[q] += 128;
  }

  const int NKT = DD / 256;  // 8 ktiles
  #pragma unroll 2
  for (int kt = 0; kt < NKT; kt++) {
    const int cur = kt & 1;
    __syncthreads();  // drains vmcnt: ktile-kt stage (issued one body ago)

    if (kt < NKT - 1) {  // prefetch kt+1 into the other buffer
      #pragma unroll
      for (int q = 0; q < 4; q++) {
        async_copy16(gA[q], &As[cur ^ 1][ldsOff[q]]);
        async_copy16(gC[q], &Cs[cur ^ 1][ldsOff[q]]);
        gA[q] += 128; gC[q] += 128;
      }
    }

    // fragments: k-step s (64 k-elems = 32B/row), lane(half,l32): 32 nibbles
    // = 16B at logical chunk s*2+half (physical ^(r&7)). fp4 uses v[0:3].
    int4v af[4][2], bf[4][2];
    #pragma unroll
    for (int s = 0; s < 4; s++) {
      #pragma unroll
      for (int i = 0; i < 2; i++) {
        const int r = wr * 64 + i * 32 + l32;
        const int pc = (s * 2 + half) ^ (r & 7);
        af[s][i] = *(const int4v*)&As[cur][r * 128 + pc * 16];
      }
      #pragma unroll
      for (int j = 0; j < 2; j++) {
        const int r = wc * 64 + j * 32 + l32;
        const int pc = (s * 2 + half) ^ (r & 7);
        bf[s][j] = *(const int4v*)&Cs[cur][r * 128 + pc * 16];
      }
    }
    #pragma unroll
    for (int s = 0; s < 4; s++)
      #pragma unroll
      for (int i = 0; i < 2; i++) {
        const int8v a8v = int8v{af[s][i][0], af[s][i][1], af[s][i][2],
                                af[s][i][3], 0, 0, 0, 0};
        #pragma unroll
        for (int j = 0; j < 2; j++) {
          const int8v b8v = int8v{bf[s][j][0], bf[s][j][1], bf[s][j][2],
                                  bf[s][j][3], 0, 0, 0, 0};
          acc[i][j] = __builtin_amdgcn_mfma_scale_f32_32x32x64_f8f6f4(
              a8v, b8v, acc[i][j], 4 /*cbsz: fp4*/, 4 /*blgp: fp4*/,
              0, 0x7F7F7F7F, 0, 0x7F7F7F7F /*E8M0 identity scales*/);
        }
      }
  }

  // epilogue: sum exp(sim/T) over this block's 128x128 tile; acc = 4096*sim.
  float local = 0.f;
  #pragma unroll
  for (int i = 0; i < 2; i++)
    #pragma unroll
    for (int j = 0; j < 2; j++)
      #pragma unroll
      for (int r = 0; r < 16; r++)
        local += __expf(acc[i][j][r] * ACC4_TO_LOGIT);
  #pragma unroll
  for (int off = 32; off > 0; off >>= 1) local += __shfl_down(local, off, 64);
  __shared__ float red[4];
  if (lane == 0) red[wave] = local;
  __syncthreads();
  if (tid == 0) S_part[br * 32 + bc] = red[0] + red[1] + red[2] + red[3];
}

// ---------------------------------------------------------------------------
// Kernel 3: tiny finalize. Separate dispatch => kernel-boundary coherence,
// so plain (non-atomic) reads of s_a/s_b/S_part are safe. 1 block.
// ---------------------------------------------------------------------------
__global__ __launch_bounds__(256) void finalize_kernel(
    const float* __restrict__ s_a, const float* __restrict__ s_b,
    const float* __restrict__ S_part, float* __restrict__ out) {
  const int tid = threadIdx.x;
  float dot = 0.f, se = 0.f;
  #pragma unroll
  for (int k = 0; k < 8; k++)
    dot += s_a[tid + 256 * k] * s_b[tid + 256 * k];
  #pragma unroll
  for (int k = 0; k < 4; k++) se += S_part[tid + 256 * k];
  #pragma unroll
  for (int off = 32; off > 0; off >>= 1) {
    dot += __shfl_down(dot, off, 64);
    se  += __shfl_down(se, off, 64);
  }
  __shared__ float redd[4], reds[4];
  if ((tid & 63) == 0) { redd[tid >> 6] = dot; reds[tid >> 6] = se; }
  __syncthreads();
  if (tid == 0) {
    const float dt = redd[0] + redd[1] + redd[2] + redd[3];
    const float st = reds[0] + reds[1] + reds[2] + reds[3];
    // loss = log(sum exp(sim_neg/T)) - mean(sim_pos)/T
    out[0] = logf(st) - dt * (INV_T / ((float)NR * (float)NR));
  }
}

extern "C" void kernel_launch(void* const* d_in, const int* in_sizes, int n_in,
                              void* d_out, int out_size, void* d_ws, size_t ws_size,
                              hipStream_t stream) {
  const float* src = (const float*)d_in[0];
  const float* bc  = (const float*)d_in[1];
  const float* raw = (const float*)d_in[2];

  char* ws = (char*)d_ws;
  unsigned int* a4 = (unsigned int*)ws;                             // 4 MiB
  unsigned int* c4 = (unsigned int*)(ws + (size_t)4 * 1024 * 1024); // 4 MiB
  float* zb  = (float*)(ws + (size_t)8 * 1024 * 1024);  // s_a | s_b (16 KiB)
  float* s_a = zb;
  float* s_b = zb + DD;
  float* S_part = (float*)(ws + (size_t)8 * 1024 * 1024 + 32 * 1024);  // 4 KiB

  zero_kernel<<<1, 256, 0, stream>>>(zb);
  normalize_colsum_kernel<<<dim3(NR / 16, 3), 256, 0, stream>>>(
      src, bc, raw, a4, c4, s_a, s_b);
  gemm_expsum_kernel<<<dim3(32, 32), 256, 0, stream>>>(
      (const unsigned char*)a4, (const unsigned char*)c4, S_part);
  finalize_kernel<<<1, 256, 0, stream>>>(s_a, s_b, S_part, (float*)d_out);
}